// Round 7
// baseline (96.810 us; speedup 1.0000x reference)
//
#include <hip/hip_runtime.h>
#include <hip/hip_bf16.h>
#include <math.h>

typedef __attribute__((ext_vector_type(4)))  short short4v;
typedef __attribute__((ext_vector_type(8)))  short short8;
typedef __attribute__((ext_vector_type(16))) float f32x16;

#define B_   2
#define N_   768
#define CN_  384
#define H_   12
#define INF_ 100000.0f
#define EPS_ 1e-7f

// ---------------- workspace layout (f32-slot offsets) ----------------
// PROJ f32 [1536][1152]  at 0        (dead after pack2; Og/OPg alias its tail)
//   Og  bf16 [1536][192] at 589824
//   OPg bf16 [1536][288] at 737280
// Qf  bf16 [24][768][32] at 1769472
// Kf  bf16 [24][768][32] at 2064384
// Vt  bf16 [24][64][768] at 2359296  (rows 40..63 never written; garbage is
//     confined to discarded acc1 regs 4..15 -- merge stores r<20 only)
// SB  bf16 [1536][384]   at 2949120  (s in bf16)
// WB  bf16 [1152][384]   at 3244032  (w_q|w_kv|w_qp|w_kvp rows, bf16)
// WOB bf16 [384][576]    at 3465216  (w_out bf16)
#define OFF_PROJ 0
#define OFF_O    589824
#define OFF_OP   737280
#define OFF_QF   1769472
#define OFF_KF   2064384
#define OFF_VT   2359296
#define OFF_SB   2949120
#define OFF_WB   3244032
#define OFF_WOB  3465216

__device__ inline float b2f(unsigned short u) {
    union { unsigned int i; float f; } x; x.i = ((unsigned int)u) << 16; return x.f;
}
__device__ inline unsigned short f2b(float f) {
    __hip_bfloat16 h = __float2bfloat16(f);
    return *reinterpret_cast<unsigned short*>(&h);
}

// ============================================================
// prep: fp32 -> bf16 operand conversion (s, Wcat rows, w_out)
// flat element space: [0,589824) s | [589824,1032192) Wcat | [...,1253376) w_out
// ============================================================
__global__ __launch_bounds__(256) void prep_kernel(
    const float* __restrict__ s,
    const float* __restrict__ w_q,  const float* __restrict__ w_kv,
    const float* __restrict__ w_qp, const float* __restrict__ w_kvp,
    const float* __restrict__ w_out,
    unsigned short* __restrict__ SB, unsigned short* __restrict__ WB,
    unsigned short* __restrict__ WOB)
{
    const long i4 = ((long)blockIdx.x * 256 + threadIdx.x) * 4;
    const float* src; unsigned short* dst; long off;
    if (i4 < 589824) {
        src = s + i4; dst = SB; off = i4;
    } else if (i4 < 1032192) {
        long e = i4 - 589824;
        int row = (int)(e / 384), c = (int)(e - (long)row * 384);
        const float* wsrc;
        if (row < 192)      wsrc = w_q   + (long)row * 384;
        else if (row < 576) wsrc = w_kv  + (long)(row - 192) * 384;
        else if (row < 720) wsrc = w_qp  + (long)(row - 576) * 384;
        else                wsrc = w_kvp + (long)(row - 720) * 384;
        src = wsrc + c; dst = WB; off = e;
    } else {
        long e = i4 - 1032192;
        src = w_out + e; dst = WOB; off = e;
    }
    float4 v = *(const float4*)src;
    short4v o;
    o[0] = (short)f2b(v.x); o[1] = (short)f2b(v.y);
    o[2] = (short)f2b(v.z); o[3] = (short)f2b(v.w);
    *(short4v*)(dst + off) = o;
}

// ============================================================
// projection GEMM (MFMA, bf16 operands): proj[1536][1152] = S @ Wcat^T + bias
// one wave per 32x32 tile. D: col=c0+(lane&31), row=r0+(reg&3)+8*(reg>>2)+4*(lane>>5)
// ============================================================
__global__ __launch_bounds__(64) void proj_mfma(
    const unsigned short* __restrict__ SB, const unsigned short* __restrict__ WB,
    const float* __restrict__ b_q,  const float* __restrict__ b_kv,
    const float* __restrict__ b_qp, const float* __restrict__ b_kvp,
    float* __restrict__ proj)
{
    const int tile = blockIdx.x;          // 48 * 36
    const int tn = tile % 36, tm = tile / 36;
    const int r0 = tm * 32, c0 = tn * 32;
    const int l  = threadIdx.x;
    const int li = l & 31, hf = l >> 5;

    const unsigned short* ap = SB + (long)(r0 + li) * CN_ + hf * 8;
    const int col = c0 + li;
    const unsigned short* wb = WB + (long)col * CN_ + hf * 8;
    const float bias = (col < 192) ? b_q[col] : (col < 576) ? b_kv[col - 192]
                     : (col < 720) ? b_qp[col - 576] : b_kvp[col - 720];

    f32x16 acc = {};
    for (int k = 0; k < CN_; k += 32) {
        short8 a0 = *(const short8*)(ap + k);
        short8 a1 = *(const short8*)(ap + k + 16);
        short8 b0 = *(const short8*)(wb + k);
        short8 b1 = *(const short8*)(wb + k + 16);
        acc = __builtin_amdgcn_mfma_f32_32x32x16_bf16(a0, b0, acc, 0, 0, 0);
        acc = __builtin_amdgcn_mfma_f32_32x32x16_bf16(a1, b1, acc, 0, 0, 0);
    }
    #pragma unroll
    for (int r = 0; r < 16; ++r) {
        int row = r0 + (r & 3) + 8 * (r >> 2) + 4 * hf;
        proj[(long)row * 1152 + col] = acc[r] + bias;
    }
}

// ============================================================
// pack2: rotate/translate + scales -> bf16 frag-ready buffers
// Qf slots: [0:16) q/sqrt48, [16:28) hw*qp, 28=1, 29=1, 30,31=0
// Kf slots: [0:16) k, [16:28) kp, 28=kc_hi, 29=kc_lo, 30,31=0
// Vt[bh][d][n]: d 0..15 = v, 16..39 = vp  (40..63 left unwritten)
// ============================================================
__global__ __launch_bounds__(256) void pack2_kernel(
    const float* __restrict__ proj,
    const float* __restrict__ rot, const float* __restrict__ trans,
    const float* __restrict__ head_weights,
    unsigned short* __restrict__ Qf, unsigned short* __restrict__ Kf,
    unsigned short* __restrict__ Vt)
{
    __shared__ float raw[1152];
    __shared__ float pk[1152];
    __shared__ float rt[12];
    __shared__ float hws[12];
    __shared__ float kcs[12];
    const int bn = blockIdx.x;
    const int t  = threadIdx.x;
    const float* rowg = proj + (long)bn * 1152;
    for (int d = t; d < 288; d += 256)
        ((float4*)raw)[d] = ((const float4*)rowg)[d];
    if (t < 9) rt[t]     = rot[bn * 9 + t];
    if (t < 3) rt[9 + t] = trans[bn * 3 + t];
    if (t < 12) {
        float v  = head_weights[t];
        float sp = (v > 20.f) ? v : log1pf(expf(v));
        hws[t] = sp * 0.13608276348795434f;  // softplus * sqrt(1/54)
    }
    __syncthreads();
    // per-head layout: h*96 + [0:16)q [16:28)qp*hw [28:44)k [44:56)kp [56:72)v [72:96)vp
    for (int slot = t; slot < 1152; slot += 256) {
        int hh = slot / 96, o = slot - hh * 96;
        float val;
        if (o < 16) {
            val = raw[hh * 16 + o] * 0.144337567297406f;  // 1/sqrt(48)
        } else if (o < 28) {
            int c = o - 16, p = c / 3, x = c - p * 3;
            float r0 = raw[576 +      hh * 4 + p];
            float r1 = raw[576 + 48 + hh * 4 + p];
            float r2 = raw[576 + 96 + hh * 4 + p];
            val = (rt[x*3]*r0 + rt[x*3+1]*r1 + rt[x*3+2]*r2 + rt[9+x]) * hws[hh];
        } else if (o < 44) {
            val = raw[192 + hh * 32 + (o - 28)];
        } else if (o < 56) {
            int c = o - 44, p = c / 3, x = c - p * 3;
            float r0 = raw[720 +       hh * 12 + p];
            float r1 = raw[720 + 144 + hh * 12 + p];
            float r2 = raw[720 + 288 + hh * 12 + p];
            val = rt[x*3]*r0 + rt[x*3+1]*r1 + rt[x*3+2]*r2 + rt[9+x];
        } else if (o < 72) {
            val = raw[192 + hh * 32 + 16 + (o - 56)];
        } else {
            int c = o - 72, p = c / 3, x = c - p * 3;
            float r0 = raw[720 +       hh * 12 + 4 + p];
            float r1 = raw[720 + 144 + hh * 12 + 4 + p];
            float r2 = raw[720 + 288 + hh * 12 + 4 + p];
            val = rt[x*3]*r0 + rt[x*3+1]*r1 + rt[x*3+2]*r2 + rt[9+x];
        }
        pk[slot] = val;
    }
    __syncthreads();
    if (t < 12) {
        float s2 = 0.f;
        #pragma unroll
        for (int e = 0; e < 12; ++e) { float v = pk[t * 96 + 44 + e]; s2 += v * v; }
        kcs[t] = -0.5f * hws[t] * s2;
    }
    __syncthreads();
    const int b = bn / N_, n = bn % N_;
    for (int d = t; d < 384; d += 256) {
        int hh = d >> 5, slot = d & 31;
        long base = ((long)(b * H_ + hh) * N_ + n) * 32 + slot;
        float qv, kv;
        if (slot < 28)      qv = pk[hh * 96 + slot];
        else if (slot < 30) qv = 1.f;
        else                qv = 0.f;
        if (slot < 16)      kv = pk[hh * 96 + 28 + slot];
        else if (slot < 28) kv = pk[hh * 96 + 44 + (slot - 16)];
        else if (slot == 28) kv = b2f(f2b(kcs[hh]));
        else if (slot == 29) kv = kcs[hh] - b2f(f2b(kcs[hh]));
        else                kv = 0.f;
        Qf[base] = f2b(qv);
        Kf[base] = f2b(kv);
    }
    for (int d = t; d < 480; d += 256) {
        int hh = d / 40, dd = d - hh * 40;
        Vt[((long)(b * H_ + hh) * 64 + dd) * N_ + n] = f2b(pk[hh * 96 + 56 + dd]);
    }
}

// ============================================================
// MFMA flash attention, mask inlined (fp32 exact). Grid (b*12+h)*24+it,
// 512 threads = 8 waves; wave w sweeps jt in [3w, 3w+3). No LDS in main loop.
// S-init: reg r of lane l gets INF*(mask[i0+(l&31)][j0+(r&3)+8*(r>>2)+4*(l>>5)]-1)
//   = four float4 loads per j-tile at j0 + {0,8,16,24} + 4*(l>>5).
// ============================================================
__global__ __launch_bounds__(512) void attn3_kernel(
    const unsigned short* __restrict__ Qf, const unsigned short* __restrict__ Kf,
    const unsigned short* __restrict__ Vt, const float* __restrict__ mask,
    unsigned short* __restrict__ Og, unsigned short* __restrict__ OPg)
{
    __shared__ float red[8][64][22];
    const int blk = blockIdx.x;
    const int it = blk % 24;
    const int bh = blk / 24;
    const int hh = bh % 12;
    const int b  = bh / 12;
    const int t  = threadIdx.x;
    const int w  = t >> 6;
    const int l  = t & 63;
    const int li = l & 31;
    const int hf = l >> 5;
    const int i0 = it * 32;

    const unsigned short* qbase = Qf + ((long)bh * N_ + i0 + li) * 32 + hf * 8;
    short8 q0 = *(const short8*)(qbase);
    short8 q1 = *(const short8*)(qbase + 16);

    f32x16 acc0 = {};
    f32x16 acc1 = {};
    float m = -1e30f, lsum = 0.f;
    const unsigned short* vtb = Vt + (long)bh * 64 * N_;
    const float* mr = mask + ((long)b * N_ + i0 + li) * N_ + hf * 4;

    for (int jt = w * 3; jt < w * 3 + 3; ++jt) {
        const int j0 = jt * 32;
        // C-init from mask (fp32, exact)
        float4 f0 = *(const float4*)(mr + j0);
        float4 f1 = *(const float4*)(mr + j0 + 8);
        float4 f2 = *(const float4*)(mr + j0 + 16);
        float4 f3 = *(const float4*)(mr + j0 + 24);
        f32x16 S;
        S[0]  = INF_*(f0.x-1.f); S[1]  = INF_*(f0.y-1.f);
        S[2]  = INF_*(f0.z-1.f); S[3]  = INF_*(f0.w-1.f);
        S[4]  = INF_*(f1.x-1.f); S[5]  = INF_*(f1.y-1.f);
        S[6]  = INF_*(f1.z-1.f); S[7]  = INF_*(f1.w-1.f);
        S[8]  = INF_*(f2.x-1.f); S[9]  = INF_*(f2.y-1.f);
        S[10] = INF_*(f2.z-1.f); S[11] = INF_*(f2.w-1.f);
        S[12] = INF_*(f3.x-1.f); S[13] = INF_*(f3.y-1.f);
        S[14] = INF_*(f3.z-1.f); S[15] = INF_*(f3.w-1.f);
        // K fragments (lane: j=li, k chunk hf*8; chunks k0..15 / k16..31)
        const unsigned short* kp = Kf + ((long)bh * N_ + j0 + li) * 32 + hf * 8;
        short8 k0 = *(const short8*)(kp);
        short8 k1 = *(const short8*)(kp + 16);
        // S^T[j][i] = sum_k K[j][k] Q[i][k]  (lane holds col i=li, 16 j rows)
        S = __builtin_amdgcn_mfma_f32_32x32x16_bf16(k0, q0, S, 0, 0, 0);
        S = __builtin_amdgcn_mfma_f32_32x32x16_bf16(k1, q1, S, 0, 0, 0);
        // online softmax for row i=li; halves exchange via permlane32_swap
        float mloc = S[0];
        #pragma unroll
        for (int r = 1; r < 16; ++r) mloc = fmaxf(mloc, S[r]);
        {
            auto mm = __builtin_amdgcn_permlane32_swap(
                __float_as_int(mloc), __float_as_int(mloc), false, false);
            mloc = fmaxf(__int_as_float(mm[0]), __int_as_float(mm[1]));
        }
        float newm = fmaxf(m, mloc);
        float scale = __expf(m - newm);
        float ps = 0.f;
        f32x16 p;
        #pragma unroll
        for (int r = 0; r < 16; ++r) { p[r] = __expf(S[r] - newm); ps += p[r]; }
        {
            auto ss = __builtin_amdgcn_permlane32_swap(
                __float_as_int(ps), __float_as_int(ps), false, false);
            ps = __int_as_float(ss[0]) + __int_as_float(ss[1]);
        }
        lsum = lsum * scale + ps;
        m = newm;
        #pragma unroll
        for (int r = 0; r < 16; ++r) acc0[r] *= scale;
        #pragma unroll
        for (int r = 0; r < 4; ++r)  acc1[r] *= scale;
        // pack p -> PV B-fragments: lane's own cvt_pk words, in order
        int c[8];
        #pragma unroll
        for (int r = 0; r < 8; ++r) {
            asm("v_cvt_pk_bf16_f32 %0, %1, %2" : "=v"(c[r]) : "v"(p[2*r]), "v"(p[2*r+1]));
        }
        union { int w4[4]; short8 v; } bf0, bf1;
        bf0.w4[0] = c[0]; bf0.w4[1] = c[1]; bf0.w4[2] = c[2]; bf0.w4[3] = c[3];
        bf1.w4[0] = c[4]; bf1.w4[1] = c[5]; bf1.w4[2] = c[6]; bf1.w4[3] = c[7];
        // V^T A-frags at the matching interleaved j offsets (two 8B loads each)
        union { short4v h[2]; short8 v; } v00, v01, v10, v11;
        const unsigned short* vr0 = vtb + (long)li * N_        + j0 + hf * 4;
        const unsigned short* vr1 = vtb + (long)(32 + li) * N_ + j0 + hf * 4;
        v00.h[0] = *(const short4v*)(vr0);       v00.h[1] = *(const short4v*)(vr0 + 8);
        v01.h[0] = *(const short4v*)(vr1);       v01.h[1] = *(const short4v*)(vr1 + 8);
        v10.h[0] = *(const short4v*)(vr0 + 16);  v10.h[1] = *(const short4v*)(vr0 + 24);
        v11.h[0] = *(const short4v*)(vr1 + 16);  v11.h[1] = *(const short4v*)(vr1 + 24);
        acc0 = __builtin_amdgcn_mfma_f32_32x32x16_bf16(v00.v, bf0.v, acc0, 0, 0, 0);
        acc1 = __builtin_amdgcn_mfma_f32_32x32x16_bf16(v01.v, bf0.v, acc1, 0, 0, 0);
        acc0 = __builtin_amdgcn_mfma_f32_32x32x16_bf16(v10.v, bf1.v, acc0, 0, 0, 0);
        acc1 = __builtin_amdgcn_mfma_f32_32x32x16_bf16(v11.v, bf1.v, acc1, 0, 0, 0);
    }
    // per-wave partials -> LDS
    float* rd = &red[w][l][0];
    rd[0] = m; rd[1] = lsum;
    #pragma unroll
    for (int r = 0; r < 16; ++r) rd[2 + r]  = acc0[r];
    #pragma unroll
    for (int r = 0; r < 4; ++r)  rd[18 + r] = acc1[r];
    __syncthreads();
    // merge 8 chunks: thread group g=t>>6 handles regs {g, g+8, g+16} of slot l2
    {
        const int l2 = t & 63, g = t >> 6;
        const int li2 = l2 & 31, hf2 = l2 >> 5;
        float ms = -1e30f;
        #pragma unroll
        for (int ww = 0; ww < 8; ++ww) ms = fmaxf(ms, red[ww][l2][0]);
        float wt[8]; float lf = 0.f;
        #pragma unroll
        for (int ww = 0; ww < 8; ++ww) {
            wt[ww] = __expf(red[ww][l2][0] - ms);
            lf += wt[ww] * red[ww][l2][1];
        }
        float inv = 1.f / lf;
        const int n = i0 + li2;
        #pragma unroll
        for (int rr = 0; rr < 3; ++rr) {
            int r = g + rr * 8;
            if (r < 20) {
                float v = 0.f;
                #pragma unroll
                for (int ww = 0; ww < 8; ++ww) v += wt[ww] * red[ww][l2][2 + r];
                v *= inv;
                int d = (r < 16) ? ((r & 3) + 8 * (r >> 2) + 4 * hf2)
                                 : (32 + (r - 16) + 4 * hf2);
                unsigned short ov = f2b(v);
                if (d < 16) Og [((long)(b * N_ + n)) * 192 + hh * 16 + d] = ov;
                else        OPg[((long)(b * N_ + n)) * 288 + hh * 24 + (d - 16)] = ov;
            }
        }
    }
}

// ============================================================
// fused cat-build + output GEMM: one wave per 32x32 out tile.
// Phase A: stage OPg tile (vector loads) + o-copy into cat LDS.
// Phase B: inverse rotation + norms -> cat LDS cols 192..575.
// Phase C: MFMA GEMM, A from LDS (row stride 584 bf16 = 1168B, 16B-aligned).
// ============================================================
__global__ __launch_bounds__(64) void out_cat_mfma(
    const unsigned short* __restrict__ Og, const unsigned short* __restrict__ OPg,
    const float* __restrict__ rot, const float* __restrict__ trans,
    const unsigned short* __restrict__ WOB, const float* __restrict__ b_out,
    float* __restrict__ out)
{
    __shared__ unsigned short cat_s[32][584];
    __shared__ unsigned short op_s[32][288];
    const int tile = blockIdx.x;          // 48 * 12
    const int tn = tile % 12, tm = tile / 12;
    const int r0 = tm * 32, c0 = tn * 32;
    const int t  = threadIdx.x;

    for (int e = t; e < 32 * 36; e += 64) {       // OPg: 36 short8 per row
        int rr = e / 36, c8 = e - rr * 36;
        *(short8*)&op_s[rr][c8 * 8] = *(const short8*)(OPg + (long)(r0 + rr) * 288 + c8 * 8);
    }
    for (int e = t; e < 32 * 24; e += 64) {       // Og: 24 short8 per row
        int rr = e / 24, c8 = e - rr * 24;
        *(short8*)&cat_s[rr][c8 * 8] = *(const short8*)(Og + (long)(r0 + rr) * 192 + c8 * 8);
    }
    __syncthreads();
    {
        const int rr = t >> 1, half = t & 1;      // 2 threads per row, 48 points each
        const long bn = r0 + rr;
        const float* rp = rot + bn * 9;
        const float* tp = trans + bn * 3;
        float R0=rp[0],R1=rp[1],R2=rp[2],R3=rp[3],R4=rp[4],R5=rp[5],R6=rp[6],R7=rp[7],R8=rp[8];
        float T0=tp[0],T1=tp[1],T2=tp[2];
        for (int p = 0; p < 48; ++p) {
            int pt = half * 48 + p;
            float g0 = b2f(op_s[rr][pt*3+0]) - T0;
            float g1 = b2f(op_s[rr][pt*3+1]) - T1;
            float g2 = b2f(op_s[rr][pt*3+2]) - T2;
            float l0 = R0*g0 + R3*g1 + R6*g2;
            float l1 = R1*g0 + R4*g1 + R7*g2;
            float l2 = R2*g0 + R5*g1 + R8*g2;
            cat_s[rr][192 + pt] = f2b(l0);
            cat_s[rr][288 + pt] = f2b(l1);
            cat_s[rr][384 + pt] = f2b(l2);
            cat_s[rr][480 + pt] = f2b(sqrtf(l0*l0 + l1*l1 + l2*l2 + EPS_));
        }
    }
    __syncthreads();
    const int li = t & 31, hf = t >> 5;
    const unsigned short* wp = WOB + (long)(c0 + li) * 576 + hf * 8;
    f32x16 acc = {};
    for (int k = 0; k < 576; k += 32) {
        short8 a0 = *(const short8*)&cat_s[li][k + hf * 8];
        short8 a1 = *(const short8*)&cat_s[li][k + 16 + hf * 8];
        short8 b0 = *(const short8*)(wp + k);
        short8 b1 = *(const short8*)(wp + k + 16);
        acc = __builtin_amdgcn_mfma_f32_32x32x16_bf16(a0, b0, acc, 0, 0, 0);
        acc = __builtin_amdgcn_mfma_f32_32x32x16_bf16(a1, b1, acc, 0, 0, 0);
    }
    float bias = b_out[c0 + li];
    #pragma unroll
    for (int r = 0; r < 16; ++r) {
        int row = r0 + (r & 3) + 8 * (r >> 2) + 4 * hf;
        out[(long)row * 384 + c0 + li] = acc[r] + bias;
    }
}

// ============================================================
extern "C" void kernel_launch(void* const* d_in, const int* in_sizes, int n_in,
                              void* d_out, int out_size, void* d_ws, size_t ws_size,
                              hipStream_t stream) {
    const float* s            = (const float*)d_in[0];
    const float* rot          = (const float*)d_in[1];
    const float* trans        = (const float*)d_in[2];
    const float* pair_mask    = (const float*)d_in[3];
    const float* w_q          = (const float*)d_in[4];
    const float* b_q          = (const float*)d_in[5];
    const float* w_kv         = (const float*)d_in[6];
    const float* b_kv         = (const float*)d_in[7];
    const float* w_qp         = (const float*)d_in[8];
    const float* b_qp         = (const float*)d_in[9];
    const float* w_kvp        = (const float*)d_in[10];
    const float* b_kvp        = (const float*)d_in[11];
    const float* head_weights = (const float*)d_in[12];
    const float* w_out        = (const float*)d_in[13];
    const float* b_out        = (const float*)d_in[14];
    float* out = (float*)d_out;
    float* ws  = (float*)d_ws;

    float*          PROJ = ws + OFF_PROJ;
    unsigned short* Og   = (unsigned short*)(ws + OFF_O);
    unsigned short* OPg  = (unsigned short*)(ws + OFF_OP);
    unsigned short* Qf   = (unsigned short*)(ws + OFF_QF);
    unsigned short* Kf   = (unsigned short*)(ws + OFF_KF);
    unsigned short* Vt   = (unsigned short*)(ws + OFF_VT);
    unsigned short* SB   = (unsigned short*)(ws + OFF_SB);
    unsigned short* WB   = (unsigned short*)(ws + OFF_WB);
    unsigned short* WOB  = (unsigned short*)(ws + OFF_WOB);

    prep_kernel<<<1224, 256, 0, stream>>>(s, w_q, w_kv, w_qp, w_kvp, w_out,
                                          SB, WB, WOB);
    proj_mfma<<<48 * 36, 64, 0, stream>>>(SB, WB, b_q, b_kv, b_qp, b_kvp, PROJ);
    pack2_kernel<<<B_ * N_, 256, 0, stream>>>(PROJ, rot, trans, head_weights,
                                              Qf, Kf, Vt);
    attn3_kernel<<<B_ * H_ * 24, 512, 0, stream>>>(Qf, Kf, Vt, pair_mask, Og, OPg);
    out_cat_mfma<<<48 * 12, 64, 0, stream>>>(Og, OPg, rot, trans, WOB, b_out, out);
}

// Round 8
// 72.194 us; speedup vs baseline: 1.3410x; 1.3410x over previous
//
#include <hip/hip_runtime.h>
#include <hip/hip_bf16.h>
#include <math.h>

typedef __attribute__((ext_vector_type(4)))  short short4v;
typedef __attribute__((ext_vector_type(8)))  short short8;
typedef __attribute__((ext_vector_type(16))) float f32x16;

#define B_   2
#define N_   768
#define CN_  384
#define H_   12
#define INF_ 100000.0f
#define EPS_ 1e-7f

// ---------------- workspace layout (f32-slot offsets) ----------------
// PROJ f32 [1536][1152]  at 0        (dead after pack2; tail reused)
//   Og  bf16 [1536][192] at 589824
//   OPg bf16 [1536][288] at 737280
//   CAT bf16 [1536][576] at 958464
// Qf  bf16 [24][768][32] at 1769472
// Kf  bf16 [24][768][32] at 2064384
// Vt  bf16 [24][64][768] at 2359296  (rows 40..63 never written; garbage is
//     confined to discarded acc1 regs 4..15 -- merge stores r<20 only)
// SB  bf16 [1536][384]   at 2949120  (s in bf16)
// WB  bf16 [1152][384]   at 3244032  (w_q|w_kv|w_qp|w_kvp rows, bf16)
// WOB bf16 [384][576]    at 3465216  (w_out bf16)
// MB  bf16 [2][24][24][64][16] at 3575808
#define OFF_PROJ 0
#define OFF_O    589824
#define OFF_OP   737280
#define OFF_CAT  958464
#define OFF_QF   1769472
#define OFF_KF   2064384
#define OFF_VT   2359296
#define OFF_SB   2949120
#define OFF_WB   3244032
#define OFF_WOB  3465216
#define OFF_MB   3575808

__device__ inline float b2f(unsigned short u) {
    union { unsigned int i; float f; } x; x.i = ((unsigned int)u) << 16; return x.f;
}
__device__ inline unsigned short f2b(float f) {
    __hip_bfloat16 h = __float2bfloat16(f);
    return *reinterpret_cast<unsigned short*>(&h);
}

// ============================================================
// prep: fp32 -> bf16 operand conversion (s, Wcat rows, w_out)
// flat element space: [0,589824) s | [589824,1032192) Wcat | [...,1253376) w_out
// ============================================================
__global__ __launch_bounds__(256) void prep_kernel(
    const float* __restrict__ s,
    const float* __restrict__ w_q,  const float* __restrict__ w_kv,
    const float* __restrict__ w_qp, const float* __restrict__ w_kvp,
    const float* __restrict__ w_out,
    unsigned short* __restrict__ SB, unsigned short* __restrict__ WB,
    unsigned short* __restrict__ WOB)
{
    const long i4 = ((long)blockIdx.x * 256 + threadIdx.x) * 4;
    const float* src; unsigned short* dst; long off;
    if (i4 < 589824) {
        src = s + i4; dst = SB; off = i4;
    } else if (i4 < 1032192) {
        long e = i4 - 589824;
        int row = (int)(e / 384), c = (int)(e - (long)row * 384);
        const float* wsrc;
        if (row < 192)      wsrc = w_q   + (long)row * 384;
        else if (row < 576) wsrc = w_kv  + (long)(row - 192) * 384;
        else if (row < 720) wsrc = w_qp  + (long)(row - 576) * 384;
        else                wsrc = w_kvp + (long)(row - 720) * 384;
        src = wsrc + c; dst = WB; off = e;
    } else {
        long e = i4 - 1032192;
        src = w_out + e; dst = WOB; off = e;
    }
    float4 v = *(const float4*)src;
    short4v o;
    o[0] = (short)f2b(v.x); o[1] = (short)f2b(v.y);
    o[2] = (short)f2b(v.z); o[3] = (short)f2b(v.w);
    *(short4v*)(dst + off) = o;
}

// ============================================================
// fused: projection GEMM (MFMA, bf16 operands, blocks 0..1727)
//      + mask-bias pack (blocks 1728..2879)
// proj: one wave per 32x32 tile of proj[1536][1152] = S @ Wcat^T + bias
//   D: col = c0 + (lane&31), row = r0 + (reg&3)+8*(reg>>2)+4*(lane>>5)
// mb:   MB[b][it][jt][64][16], entry (l,reg) =
//   INF*(mask[b][i0+(l&31)][j0+(reg&3)+8*(reg>>2)+4*(l>>5)] - 1); thread t = l.
// ============================================================
__global__ __launch_bounds__(64) void proj_mb_kernel(
    const unsigned short* __restrict__ SB, const unsigned short* __restrict__ WB,
    const float* __restrict__ b_q,  const float* __restrict__ b_kv,
    const float* __restrict__ b_qp, const float* __restrict__ b_kvp,
    const float* __restrict__ mask,
    float* __restrict__ proj, unsigned short* __restrict__ MB)
{
    if (blockIdx.x >= 1728) {
        // ---- mask-bias pack ----
        const int tile = blockIdx.x - 1728;   // b*576 + it*24 + jt
        const int jt = tile % 24;
        const int it = (tile / 24) % 24;
        const int b  = tile / 576;
        const int tt = threadIdx.x;           // == l
        const int i0 = it * 32, j0 = jt * 32;
        const float* mrow = mask + ((long)b * N_ + i0 + (tt & 31)) * N_
                          + j0 + (tt >> 5) * 4;
        union { unsigned short u[16]; short8 v[2]; } o;
        #pragma unroll
        for (int g = 0; g < 4; ++g) {         // j-groups 0,8,16,24
            float4 mv = *(const float4*)(mrow + 8 * g);
            o.u[g*4+0] = f2b(INF_ * (mv.x - 1.f));
            o.u[g*4+1] = f2b(INF_ * (mv.y - 1.f));
            o.u[g*4+2] = f2b(INF_ * (mv.z - 1.f));
            o.u[g*4+3] = f2b(INF_ * (mv.w - 1.f));
        }
        unsigned short* outp = MB + (long)tile * 1024 + tt * 16;
        *(short8*)(outp)     = o.v[0];
        *(short8*)(outp + 8) = o.v[1];
        return;
    }
    // ---- projection GEMM ----
    const int tile = blockIdx.x;          // 48 * 36
    const int tn = tile % 36, tm = tile / 36;
    const int r0 = tm * 32, c0 = tn * 32;
    const int l  = threadIdx.x;
    const int li = l & 31, hf = l >> 5;

    const unsigned short* ap = SB + (long)(r0 + li) * CN_ + hf * 8;
    const int col = c0 + li;
    const unsigned short* wb = WB + (long)col * CN_ + hf * 8;
    const float bias = (col < 192) ? b_q[col] : (col < 576) ? b_kv[col - 192]
                     : (col < 720) ? b_qp[col - 576] : b_kvp[col - 720];

    f32x16 acc = {};
    for (int k = 0; k < CN_; k += 32) {
        short8 a0 = *(const short8*)(ap + k);
        short8 a1 = *(const short8*)(ap + k + 16);
        short8 b0 = *(const short8*)(wb + k);
        short8 b1 = *(const short8*)(wb + k + 16);
        acc = __builtin_amdgcn_mfma_f32_32x32x16_bf16(a0, b0, acc, 0, 0, 0);
        acc = __builtin_amdgcn_mfma_f32_32x32x16_bf16(a1, b1, acc, 0, 0, 0);
    }
    #pragma unroll
    for (int r = 0; r < 16; ++r) {
        int row = r0 + (r & 3) + 8 * (r >> 2) + 4 * hf;
        proj[(long)row * 1152 + col] = acc[r] + bias;
    }
}

// ============================================================
// pack2: rotate/translate + scales -> bf16 frag-ready buffers
// Qf slots: [0:16) q/sqrt48, [16:28) hw*qp, 28=1, 29=1, 30,31=0
// Kf slots: [0:16) k, [16:28) kp, 28=kc_hi, 29=kc_lo, 30,31=0
// Vt[bh][d][n]: d 0..15 = v, 16..39 = vp  (40..63 left unwritten)
// ============================================================
__global__ __launch_bounds__(256) void pack2_kernel(
    const float* __restrict__ proj,
    const float* __restrict__ rot, const float* __restrict__ trans,
    const float* __restrict__ head_weights,
    unsigned short* __restrict__ Qf, unsigned short* __restrict__ Kf,
    unsigned short* __restrict__ Vt)
{
    __shared__ float raw[1152];
    __shared__ float pk[1152];
    __shared__ float rt[12];
    __shared__ float hws[12];
    __shared__ float kcs[12];
    const int bn = blockIdx.x;
    const int t  = threadIdx.x;
    const float* rowg = proj + (long)bn * 1152;
    for (int d = t; d < 288; d += 256)
        ((float4*)raw)[d] = ((const float4*)rowg)[d];
    if (t < 9) rt[t]     = rot[bn * 9 + t];
    if (t < 3) rt[9 + t] = trans[bn * 3 + t];
    if (t < 12) {
        float v  = head_weights[t];
        float sp = (v > 20.f) ? v : log1pf(expf(v));
        hws[t] = sp * 0.13608276348795434f;  // softplus * sqrt(1/54)
    }
    __syncthreads();
    // per-head layout: h*96 + [0:16)q [16:28)qp*hw [28:44)k [44:56)kp [56:72)v [72:96)vp
    for (int slot = t; slot < 1152; slot += 256) {
        int hh = slot / 96, o = slot - hh * 96;
        float val;
        if (o < 16) {
            val = raw[hh * 16 + o] * 0.144337567297406f;  // 1/sqrt(48)
        } else if (o < 28) {
            int c = o - 16, p = c / 3, x = c - p * 3;
            float r0 = raw[576 +      hh * 4 + p];
            float r1 = raw[576 + 48 + hh * 4 + p];
            float r2 = raw[576 + 96 + hh * 4 + p];
            val = (rt[x*3]*r0 + rt[x*3+1]*r1 + rt[x*3+2]*r2 + rt[9+x]) * hws[hh];
        } else if (o < 44) {
            val = raw[192 + hh * 32 + (o - 28)];
        } else if (o < 56) {
            int c = o - 44, p = c / 3, x = c - p * 3;
            float r0 = raw[720 +       hh * 12 + p];
            float r1 = raw[720 + 144 + hh * 12 + p];
            float r2 = raw[720 + 288 + hh * 12 + p];
            val = rt[x*3]*r0 + rt[x*3+1]*r1 + rt[x*3+2]*r2 + rt[9+x];
        } else if (o < 72) {
            val = raw[192 + hh * 32 + 16 + (o - 56)];
        } else {
            int c = o - 72, p = c / 3, x = c - p * 3;
            float r0 = raw[720 +       hh * 12 + 4 + p];
            float r1 = raw[720 + 144 + hh * 12 + 4 + p];
            float r2 = raw[720 + 288 + hh * 12 + 4 + p];
            val = rt[x*3]*r0 + rt[x*3+1]*r1 + rt[x*3+2]*r2 + rt[9+x];
        }
        pk[slot] = val;
    }
    __syncthreads();
    if (t < 12) {
        float s2 = 0.f;
        #pragma unroll
        for (int e = 0; e < 12; ++e) { float v = pk[t * 96 + 44 + e]; s2 += v * v; }
        kcs[t] = -0.5f * hws[t] * s2;
    }
    __syncthreads();
    const int b = bn / N_, n = bn % N_;
    for (int d = t; d < 384; d += 256) {
        int hh = d >> 5, slot = d & 31;
        long base = ((long)(b * H_ + hh) * N_ + n) * 32 + slot;
        float qv, kv;
        if (slot < 28)      qv = pk[hh * 96 + slot];
        else if (slot < 30) qv = 1.f;
        else                qv = 0.f;
        if (slot < 16)      kv = pk[hh * 96 + 28 + slot];
        else if (slot < 28) kv = pk[hh * 96 + 44 + (slot - 16)];
        else if (slot == 28) kv = b2f(f2b(kcs[hh]));
        else if (slot == 29) kv = kcs[hh] - b2f(f2b(kcs[hh]));
        else                kv = 0.f;
        Qf[base] = f2b(qv);
        Kf[base] = f2b(kv);
    }
    for (int d = t; d < 480; d += 256) {
        int hh = d / 40, dd = d - hh * 40;
        Vt[((long)(b * H_ + hh) * 64 + dd) * N_ + n] = f2b(pk[hh * 96 + 56 + dd]);
    }
}

// ============================================================
// MFMA flash attention. Grid (b*12+h)*24+it, 512 threads = 8 waves.
// Wave w sweeps j in [w*96, w*96+96). No LDS in main loop; merge at end.
// Vt rows 40..63 are uninitialized: they feed only acc1 regs 4..15,
// which are never stored (merge handles r<20; acc1 contributes r=16..19).
// ============================================================
__global__ __launch_bounds__(512) void attn2_kernel(
    const unsigned short* __restrict__ Qf, const unsigned short* __restrict__ Kf,
    const unsigned short* __restrict__ Vt, const unsigned short* __restrict__ MB,
    unsigned short* __restrict__ Og, unsigned short* __restrict__ OPg)
{
    __shared__ float red[8][64][22];
    const int blk = blockIdx.x;
    const int it = blk % 24;
    const int bh = blk / 24;
    const int hh = bh % 12;
    const int b  = bh / 12;
    const int t  = threadIdx.x;
    const int w  = t >> 6;
    const int l  = t & 63;
    const int li = l & 31;
    const int hf = l >> 5;
    const int i0 = it * 32;

    const unsigned short* qbase = Qf + ((long)bh * N_ + i0 + li) * 32 + hf * 8;
    short8 q0 = *(const short8*)(qbase);
    short8 q1 = *(const short8*)(qbase + 16);

    f32x16 acc0 = {};
    f32x16 acc1 = {};
    float m = -1e30f, lsum = 0.f;
    const unsigned short* vtb = Vt + (long)bh * 64 * N_;
    const unsigned short* mbb = MB + ((long)(b * 24 + it)) * 24 * 1024;

    for (int jt = w * 3; jt < w * 3 + 3; ++jt) {
        const int j0 = jt * 32;
        // C-init from mask-bias fragments
        const unsigned short* mbp = mbb + (long)jt * 1024 + l * 16;
        short8 mb0 = *(const short8*)(mbp);
        short8 mb1 = *(const short8*)(mbp + 8);
        f32x16 S;
        #pragma unroll
        for (int r = 0; r < 8; ++r) S[r]     = b2f((unsigned short)mb0[r]);
        #pragma unroll
        for (int r = 0; r < 8; ++r) S[8 + r] = b2f((unsigned short)mb1[r]);
        // K fragments (lane: j=li, k chunk hf*8; chunks k0..15 / k16..31)
        const unsigned short* kp = Kf + ((long)bh * N_ + j0 + li) * 32 + hf * 8;
        short8 k0 = *(const short8*)(kp);
        short8 k1 = *(const short8*)(kp + 16);
        // S^T[j][i] = sum_k K[j][k] Q[i][k]  (lane holds col i=li, 16 j rows)
        S = __builtin_amdgcn_mfma_f32_32x32x16_bf16(k0, q0, S, 0, 0, 0);
        S = __builtin_amdgcn_mfma_f32_32x32x16_bf16(k1, q1, S, 0, 0, 0);
        // online softmax for row i=li; halves exchange via permlane32_swap.
        float mloc = S[0];
        #pragma unroll
        for (int r = 1; r < 16; ++r) mloc = fmaxf(mloc, S[r]);
        {
            auto mm = __builtin_amdgcn_permlane32_swap(
                __float_as_int(mloc), __float_as_int(mloc), false, false);
            mloc = fmaxf(__int_as_float(mm[0]), __int_as_float(mm[1]));
        }
        float newm = fmaxf(m, mloc);
        float scale = __expf(m - newm);
        float ps = 0.f;
        f32x16 p;
        #pragma unroll
        for (int r = 0; r < 16; ++r) { p[r] = __expf(S[r] - newm); ps += p[r]; }
        {
            auto ss = __builtin_amdgcn_permlane32_swap(
                __float_as_int(ps), __float_as_int(ps), false, false);
            ps = __int_as_float(ss[0]) + __int_as_float(ss[1]);
        }
        lsum = lsum * scale + ps;
        m = newm;
        #pragma unroll
        for (int r = 0; r < 16; ++r) acc0[r] *= scale;
        #pragma unroll
        for (int r = 0; r < 4; ++r)  acc1[r] *= scale;
        // pack p -> PV B-fragments: lane's own cvt_pk words, in order.
        int c[8];
        #pragma unroll
        for (int r = 0; r < 8; ++r) {
            asm("v_cvt_pk_bf16_f32 %0, %1, %2" : "=v"(c[r]) : "v"(p[2*r]), "v"(p[2*r+1]));
        }
        union { int w4[4]; short8 v; } bf0, bf1;
        bf0.w4[0] = c[0]; bf0.w4[1] = c[1]; bf0.w4[2] = c[2]; bf0.w4[3] = c[3];
        bf1.w4[0] = c[4]; bf1.w4[1] = c[5]; bf1.w4[2] = c[6]; bf1.w4[3] = c[7];
        // V^T A-frags at the matching interleaved j offsets (two 8B loads each)
        union { short4v h[2]; short8 v; } v00, v01, v10, v11;
        const unsigned short* vr0 = vtb + (long)li * N_        + j0 + hf * 4;
        const unsigned short* vr1 = vtb + (long)(32 + li) * N_ + j0 + hf * 4;
        v00.h[0] = *(const short4v*)(vr0);       v00.h[1] = *(const short4v*)(vr0 + 8);
        v01.h[0] = *(const short4v*)(vr1);       v01.h[1] = *(const short4v*)(vr1 + 8);
        v10.h[0] = *(const short4v*)(vr0 + 16);  v10.h[1] = *(const short4v*)(vr0 + 24);
        v11.h[0] = *(const short4v*)(vr1 + 16);  v11.h[1] = *(const short4v*)(vr1 + 24);
        acc0 = __builtin_amdgcn_mfma_f32_32x32x16_bf16(v00.v, bf0.v, acc0, 0, 0, 0);
        acc1 = __builtin_amdgcn_mfma_f32_32x32x16_bf16(v01.v, bf0.v, acc1, 0, 0, 0);
        acc0 = __builtin_amdgcn_mfma_f32_32x32x16_bf16(v10.v, bf1.v, acc0, 0, 0, 0);
        acc1 = __builtin_amdgcn_mfma_f32_32x32x16_bf16(v11.v, bf1.v, acc1, 0, 0, 0);
    }
    // per-wave partials -> LDS
    float* rd = &red[w][l][0];
    rd[0] = m; rd[1] = lsum;
    #pragma unroll
    for (int r = 0; r < 16; ++r) rd[2 + r]  = acc0[r];
    #pragma unroll
    for (int r = 0; r < 4; ++r)  rd[18 + r] = acc1[r];
    __syncthreads();
    // merge 8 chunks: thread group g=t>>6 handles regs {g, g+8, g+16} of slot l2
    {
        const int l2 = t & 63, g = t >> 6;
        const int li2 = l2 & 31, hf2 = l2 >> 5;
        float ms = -1e30f;
        #pragma unroll
        for (int ww = 0; ww < 8; ++ww) ms = fmaxf(ms, red[ww][l2][0]);
        float wt[8]; float lf = 0.f;
        #pragma unroll
        for (int ww = 0; ww < 8; ++ww) {
            wt[ww] = __expf(red[ww][l2][0] - ms);
            lf += wt[ww] * red[ww][l2][1];
        }
        float inv = 1.f / lf;
        const int n = i0 + li2;
        #pragma unroll
        for (int rr = 0; rr < 3; ++rr) {
            int r = g + rr * 8;
            if (r < 20) {
                float v = 0.f;
                #pragma unroll
                for (int ww = 0; ww < 8; ++ww) v += wt[ww] * red[ww][l2][2 + r];
                v *= inv;
                int d = (r < 16) ? ((r & 3) + 8 * (r >> 2) + 4 * hf2)
                                 : (32 + (r - 16) + 4 * hf2);
                unsigned short ov = f2b(v);
                if (d < 16) Og [((long)(b * N_ + n)) * 192 + hh * 16 + d] = ov;
                else        OPg[((long)(b * N_ + n)) * 288 + hh * 24 + (d - 16)] = ov;
            }
        }
    }
}

// ============================================================
// cat build: inverse rotation + norms -> cat[1536][576] bf16
// ============================================================
__global__ __launch_bounds__(128) void cat_kernel(
    const unsigned short* __restrict__ Og, const unsigned short* __restrict__ OPg,
    const float* __restrict__ rot, const float* __restrict__ trans,
    unsigned short* __restrict__ catg)
{
    __shared__ float cat[576];
    __shared__ float rt[12];
    const int bn = blockIdx.x;
    const int t  = threadIdx.x;
    if (t < 9) rt[t]     = rot[bn * 9 + t];
    if (t < 3) rt[9 + t] = trans[bn * 3 + t];
    for (int d = t; d < 192; d += 128) cat[d] = b2f(Og[(long)bn * 192 + d]);
    __syncthreads();
    if (t < 96) {
        float g0 = b2f(OPg[(long)bn * 288 + t * 3 + 0]) - rt[9];
        float g1 = b2f(OPg[(long)bn * 288 + t * 3 + 1]) - rt[10];
        float g2 = b2f(OPg[(long)bn * 288 + t * 3 + 2]) - rt[11];
        float l0 = rt[0]*g0 + rt[3]*g1 + rt[6]*g2;
        float l1 = rt[1]*g0 + rt[4]*g1 + rt[7]*g2;
        float l2 = rt[2]*g0 + rt[5]*g1 + rt[8]*g2;
        cat[192 + t] = l0;
        cat[288 + t] = l1;
        cat[384 + t] = l2;
        cat[480 + t] = sqrtf(l0*l0 + l1*l1 + l2*l2 + EPS_);
    }
    __syncthreads();
    for (int d = t; d < 576; d += 128) catg[(long)bn * 576 + d] = f2b(cat[d]);
}

// ============================================================
// output GEMM (MFMA, bf16 operands): out[1536][384] = cat @ w_out^T + b_out
// one wave per 32x32 tile.
// ============================================================
__global__ __launch_bounds__(64) void out_mfma(
    const unsigned short* __restrict__ catg,  // [1536][576] bf16
    const unsigned short* __restrict__ WOB,   // [384][576] bf16
    const float* __restrict__ b_out,
    float* __restrict__ out)
{
    const int tile = blockIdx.x;          // 48 * 12
    const int tn = tile % 12, tm = tile / 12;
    const int r0 = tm * 32, c0 = tn * 32;
    const int l  = threadIdx.x;
    const int li = l & 31, hf = l >> 5;

    const unsigned short* ap = catg + (long)(r0 + li) * 576 + hf * 8;
    const unsigned short* wp = WOB + (long)(c0 + li) * 576 + hf * 8;

    f32x16 acc = {};
    for (int k = 0; k < 576; k += 32) {
        short8 a0 = *(const short8*)(ap + k);
        short8 a1 = *(const short8*)(ap + k + 16);
        short8 b0 = *(const short8*)(wp + k);
        short8 b1 = *(const short8*)(wp + k + 16);
        acc = __builtin_amdgcn_mfma_f32_32x32x16_bf16(a0, b0, acc, 0, 0, 0);
        acc = __builtin_amdgcn_mfma_f32_32x32x16_bf16(a1, b1, acc, 0, 0, 0);
    }
    float bias = b_out[c0 + li];
    #pragma unroll
    for (int r = 0; r < 16; ++r) {
        int row = r0 + (r & 3) + 8 * (r >> 2) + 4 * hf;
        out[(long)row * 384 + c0 + li] = acc[r] + bias;
    }
}

// ============================================================
extern "C" void kernel_launch(void* const* d_in, const int* in_sizes, int n_in,
                              void* d_out, int out_size, void* d_ws, size_t ws_size,
                              hipStream_t stream) {
    const float* s            = (const float*)d_in[0];
    const float* rot          = (const float*)d_in[1];
    const float* trans        = (const float*)d_in[2];
    const float* pair_mask    = (const float*)d_in[3];
    const float* w_q          = (const float*)d_in[4];
    const float* b_q          = (const float*)d_in[5];
    const float* w_kv         = (const float*)d_in[6];
    const float* b_kv         = (const float*)d_in[7];
    const float* w_qp         = (const float*)d_in[8];
    const float* b_qp         = (const float*)d_in[9];
    const float* w_kvp        = (const float*)d_in[10];
    const float* b_kvp        = (const float*)d_in[11];
    const float* head_weights = (const float*)d_in[12];
    const float* w_out        = (const float*)d_in[13];
    const float* b_out        = (const float*)d_in[14];
    float* out = (float*)d_out;
    float* ws  = (float*)d_ws;

    float*          PROJ = ws + OFF_PROJ;
    unsigned short* Og   = (unsigned short*)(ws + OFF_O);
    unsigned short* OPg  = (unsigned short*)(ws + OFF_OP);
    unsigned short* CAT  = (unsigned short*)(ws + OFF_CAT);
    unsigned short* Qf   = (unsigned short*)(ws + OFF_QF);
    unsigned short* Kf   = (unsigned short*)(ws + OFF_KF);
    unsigned short* Vt   = (unsigned short*)(ws + OFF_VT);
    unsigned short* SB   = (unsigned short*)(ws + OFF_SB);
    unsigned short* WB   = (unsigned short*)(ws + OFF_WB);
    unsigned short* WOB  = (unsigned short*)(ws + OFF_WOB);
    unsigned short* MBp  = (unsigned short*)(ws + OFF_MB);

    prep_kernel<<<1224, 256, 0, stream>>>(s, w_q, w_kv, w_qp, w_kvp, w_out,
                                          SB, WB, WOB);
    proj_mb_kernel<<<48 * 36 + B_ * 24 * 24, 64, 0, stream>>>(
        SB, WB, b_q, b_kv, b_qp, b_kvp, pair_mask, PROJ, MBp);
    pack2_kernel<<<B_ * N_, 256, 0, stream>>>(PROJ, rot, trans, head_weights,
                                              Qf, Kf, Vt);
    attn2_kernel<<<B_ * H_ * 24, 512, 0, stream>>>(Qf, Kf, Vt, MBp, Og, OPg);
    cat_kernel<<<B_ * N_, 128, 0, stream>>>(Og, OPg, rot, trans, CAT);
    out_mfma<<<48 * 12, 64, 0, stream>>>(CAT, WOB, b_out, out);
}